// Round 4
// baseline (386.317 us; speedup 1.0000x reference)
//
#include <hip/hip_runtime.h>

// MoE combine: out[t] = sum_k w[t,k] * moe_output[mapped_slots[t,k]]
// w = scores / (sum_k scores + eps)
// T=8192 tokens, K=2, H=4096 fp32. Pure memory-bound gather-combine.
// Floor: ~384 MiB traffic / 6.3 TB/s ~= 61 us.

constexpr int HIDDEN   = 4096;
constexpr int N_TOKENS = 8192;
constexpr float EPS    = 1e-9f;

// Native clang vector (not HIP_vector_type) so nontemporal builtins accept it.
typedef float f32x4 __attribute__((ext_vector_type(4)));

__global__ __launch_bounds__(256) void moe_combine_kernel(
    const float* __restrict__ moe_output,   // [N_SLOTS, HIDDEN]
    const float* __restrict__ scores,       // [T, 2]
    const int*   __restrict__ mapped_slots, // [T, 2] (int32 on device)
    float*       __restrict__ out)          // [T, HIDDEN]
{
    const int t = blockIdx.x;

    // Per-token scalars: broadcast loads, cached in L1/L2.
    const float s0  = scores[t * 2 + 0];
    const float s1  = scores[t * 2 + 1];
    const float inv = 1.0f / (s0 + s1 + EPS);
    const float w0  = s0 * inv;
    const float w1  = s1 * inv;

    const long long slot0 = (long long)mapped_slots[t * 2 + 0];
    const long long slot1 = (long long)mapped_slots[t * 2 + 1];

    const f32x4* __restrict__ a0 =
        reinterpret_cast<const f32x4*>(moe_output + slot0 * HIDDEN);
    const f32x4* __restrict__ a1 =
        reinterpret_cast<const f32x4*>(moe_output + slot1 * HIDDEN);
    f32x4* __restrict__ o =
        reinterpret_cast<f32x4*>(out + (long long)t * HIDDEN);

    // HIDDEN/4 = 1024 float4 per row; 256 threads -> 4 iters/thread.
    // Output is write-once: nontemporal stores keep the 128 MiB out
    // stream from evicting gathered moe_output rows in L2/L3
    // (duplicate slots -> cache re-hits are real read savings).
    #pragma unroll
    for (int i = threadIdx.x; i < HIDDEN / 4; i += 256) {
        const f32x4 v0 = a0[i];
        const f32x4 v1 = a1[i];
        f32x4 r = w0 * v0 + w1 * v1;
        __builtin_nontemporal_store(r, &o[i]);
    }
}

extern "C" void kernel_launch(void* const* d_in, const int* in_sizes, int n_in,
                              void* d_out, int out_size, void* d_ws, size_t ws_size,
                              hipStream_t stream) {
    const float* moe_output   = (const float*)d_in[0];
    const float* scores       = (const float*)d_in[1];
    const int*   mapped_slots = (const int*)d_in[2];
    // d_in[3] = expert_counts: unused by the reference computation.
    float* out = (float*)d_out;

    moe_combine_kernel<<<N_TOKENS, 256, 0, stream>>>(
        moe_output, scores, mapped_slots, out);
}

// Round 9
// 384.883 us; speedup vs baseline: 1.0037x; 1.0037x over previous
//
#include <hip/hip_runtime.h>

// MoE combine: out[t] = sum_k w[t,k] * moe_output[mapped_slots[t,k]]
// w = scores / (sum_k scores + eps)
// T=8192 tokens, K=2, H=4096 fp32. Pure memory-bound gather-combine.
// Floor: ~384 MiB traffic / 6.3 TB/s ~= 61 us (47 us if L3 absorbs
// duplicate-slot row reads; ~37% of gathers are duplicates in expectation).
//
// R4 evidence: kernel dispatch < 162 us (absent from rocprof top-5, which is
// all ~163us 1-GiB harness poison fills at 82% peak BW); reported dur_us=386
// includes harness restore/poison. Only Δdur_us between rounds is meaningful.
// R5 experiment: nontemporal store -> plain store (single variable).

constexpr int HIDDEN   = 4096;
constexpr int N_TOKENS = 8192;
constexpr float EPS    = 1e-9f;

typedef float f32x4 __attribute__((ext_vector_type(4)));

__global__ __launch_bounds__(256) void moe_combine_kernel(
    const float* __restrict__ moe_output,   // [N_SLOTS, HIDDEN]
    const float* __restrict__ scores,       // [T, 2]
    const int*   __restrict__ mapped_slots, // [T, 2] (int32 on device)
    float*       __restrict__ out)          // [T, HIDDEN]
{
    const int t = blockIdx.x;

    // Per-token scalars: broadcast loads, cached in L1/L2.
    const float s0  = scores[t * 2 + 0];
    const float s1  = scores[t * 2 + 1];
    const float inv = 1.0f / (s0 + s1 + EPS);
    const float w0  = s0 * inv;
    const float w1  = s1 * inv;

    const long long slot0 = (long long)mapped_slots[t * 2 + 0];
    const long long slot1 = (long long)mapped_slots[t * 2 + 1];

    const f32x4* __restrict__ a0 =
        reinterpret_cast<const f32x4*>(moe_output + slot0 * HIDDEN);
    const f32x4* __restrict__ a1 =
        reinterpret_cast<const f32x4*>(moe_output + slot1 * HIDDEN);
    f32x4* __restrict__ o =
        reinterpret_cast<f32x4*>(out + (long long)t * HIDDEN);

    // HIDDEN/4 = 1024 float4 per row; 256 threads -> 4 iters/thread.
    // Plain coalesced dwordx4 stores this round (A/B vs R4's nontemporal).
    #pragma unroll
    for (int i = threadIdx.x; i < HIDDEN / 4; i += 256) {
        const f32x4 v0 = a0[i];
        const f32x4 v1 = a1[i];
        o[i] = w0 * v0 + w1 * v1;
    }
}

extern "C" void kernel_launch(void* const* d_in, const int* in_sizes, int n_in,
                              void* d_out, int out_size, void* d_ws, size_t ws_size,
                              hipStream_t stream) {
    const float* moe_output   = (const float*)d_in[0];
    const float* scores       = (const float*)d_in[1];
    const int*   mapped_slots = (const int*)d_in[2];
    // d_in[3] = expert_counts: unused by the reference computation.
    float* out = (float*)d_out;

    moe_combine_kernel<<<N_TOKENS, 256, 0, stream>>>(
        moe_output, scores, mapped_slots, out);
}